// Round 1
// baseline (252.105 us; speedup 1.0000x reference)
//
#include <hip/hip_runtime.h>
#include <math.h>

// Problem constants (from reference: n=8192, d=4096, fp32)
#define NROWS 8192
#define NCOLS 4096
#define TEMPERATURE 100.0f

// ---------------- Kernel 1: column sum (partial, atomic accumulate) --------
// grid: (NCOLS/1024, ROW_CHUNKS), block: 256 threads, each thread owns 4 cols
#define ROW_CHUNKS 128
#define ROWS_PER_CHUNK (NROWS / ROW_CHUNKS)   // 64

__global__ __launch_bounds__(256)
void colsum_kernel(const float* __restrict__ g, float* __restrict__ colsum) {
    const int col  = (blockIdx.x * 256 + threadIdx.x) * 4;
    const int row0 = blockIdx.y * ROWS_PER_CHUNK;
    const float* p = g + (size_t)row0 * NCOLS + col;
    float4 acc = make_float4(0.f, 0.f, 0.f, 0.f);
    #pragma unroll 4
    for (int r = 0; r < ROWS_PER_CHUNK; ++r) {
        float4 v = *reinterpret_cast<const float4*>(p);
        acc.x += v.x; acc.y += v.y; acc.z += v.z; acc.w += v.w;
        p += NCOLS;
    }
    atomicAdd(&colsum[col + 0], acc.x);
    atomicAdd(&colsum[col + 1], acc.y);
    atomicAdd(&colsum[col + 2], acc.z);
    atomicAdd(&colsum[col + 3], acc.w);
}

// ---------------- Kernel 2: scores[i] = G[i,:] . colsum ---------------------
// one wave (64 lanes) per row; colsum staged in LDS; grid NROWS/4, block 256
__global__ __launch_bounds__(256)
void scores_kernel(const float* __restrict__ g, const float* __restrict__ colsum,
                   float* __restrict__ scores) {
    __shared__ float cs[NCOLS];
    for (int i = threadIdx.x; i < NCOLS / 4; i += 256) {
        reinterpret_cast<float4*>(cs)[i] =
            reinterpret_cast<const float4*>(colsum)[i];
    }
    __syncthreads();

    const int wave = threadIdx.x >> 6;
    const int lane = threadIdx.x & 63;
    const int row  = blockIdx.x * 4 + wave;
    const float* p = g + (size_t)row * NCOLS;

    float acc = 0.f;
    #pragma unroll
    for (int k = 0; k < NCOLS / 256; ++k) {      // 16 iterations
        const int c = k * 256 + lane * 4;
        float4 v = *reinterpret_cast<const float4*>(p + c);
        float4 w = *reinterpret_cast<const float4*>(cs + c);
        acc += v.x * w.x + v.y * w.y + v.z * w.z + v.w * w.w;
    }
    #pragma unroll
    for (int off = 32; off > 0; off >>= 1) acc += __shfl_xor(acc, off, 64);
    if (lane == 0) scores[row] = acc;
}

// ---------------- Kernel 3: softmax over 8192 scores (single block) ---------
// block: 1024 threads, 8 scores each
__global__ __launch_bounds__(1024)
void softmax_kernel(const float* __restrict__ scores, float* __restrict__ w) {
    __shared__ float red[16];
    const int tid = threadIdx.x;

    float local[8];
    float m = -INFINITY;
    #pragma unroll
    for (int k = 0; k < 8; ++k) {
        local[k] = scores[tid + k * 1024];
        m = fmaxf(m, local[k]);
    }
    #pragma unroll
    for (int off = 32; off > 0; off >>= 1) m = fmaxf(m, __shfl_xor(m, off, 64));
    if ((tid & 63) == 0) red[tid >> 6] = m;
    __syncthreads();
    float gm = red[0];
    #pragma unroll
    for (int i = 1; i < 16; ++i) gm = fmaxf(gm, red[i]);
    __syncthreads();   // everyone done reading red before reuse

    float e[8];
    float s = 0.f;
    #pragma unroll
    for (int k = 0; k < 8; ++k) {
        e[k] = __expf((local[k] - gm) * (1.0f / TEMPERATURE));
        s += e[k];
    }
    #pragma unroll
    for (int off = 32; off > 0; off >>= 1) s += __shfl_xor(s, off, 64);
    if ((tid & 63) == 0) red[tid >> 6] = s;
    __syncthreads();
    float total = 0.f;
    #pragma unroll
    for (int i = 0; i < 16; ++i) total += red[i];

    const float inv = 1.0f / total;
    #pragma unroll
    for (int k = 0; k < 8; ++k) w[tid + k * 1024] = e[k] * inv;
}

// ---------------- Kernel 4: out[d] = sum_i w[i] * G[i,d] --------------------
__global__ __launch_bounds__(256)
void pool_kernel(const float* __restrict__ g, const float* __restrict__ w,
                 float* __restrict__ out) {
    const int col  = (blockIdx.x * 256 + threadIdx.x) * 4;
    const int row0 = blockIdx.y * ROWS_PER_CHUNK;
    const float* p = g + (size_t)row0 * NCOLS + col;
    float4 acc = make_float4(0.f, 0.f, 0.f, 0.f);
    #pragma unroll 4
    for (int r = 0; r < ROWS_PER_CHUNK; ++r) {
        const float wt = w[row0 + r];
        float4 v = *reinterpret_cast<const float4*>(p);
        acc.x += wt * v.x; acc.y += wt * v.y;
        acc.z += wt * v.z; acc.w += wt * v.w;
        p += NCOLS;
    }
    atomicAdd(&out[col + 0], acc.x);
    atomicAdd(&out[col + 1], acc.y);
    atomicAdd(&out[col + 2], acc.z);
    atomicAdd(&out[col + 3], acc.w);
}

extern "C" void kernel_launch(void* const* d_in, const int* in_sizes, int n_in,
                              void* d_out, int out_size, void* d_ws, size_t ws_size,
                              hipStream_t stream) {
    const float* grad = (const float*)d_in[0];
    float* out = (float*)d_out;

    // ws layout: colsum [0, 4096), scores [4096, 12288), w [12288, 20480)
    float* colsum = (float*)d_ws;
    float* scores = colsum + NCOLS;
    float* wgt    = scores + NROWS;

    // zero accumulators (ws and d_out are poisoned 0xAA before every launch)
    hipMemsetAsync(colsum, 0, NCOLS * sizeof(float), stream);
    hipMemsetAsync(out, 0, NCOLS * sizeof(float), stream);

    dim3 grid1(NCOLS / 1024, ROW_CHUNKS);
    colsum_kernel<<<grid1, 256, 0, stream>>>(grad, colsum);

    scores_kernel<<<NROWS / 4, 256, 0, stream>>>(grad, colsum, scores);

    softmax_kernel<<<1, 1024, 0, stream>>>(scores, wgt);

    pool_kernel<<<grid1, 256, 0, stream>>>(grad, wgt, out);
}

// Round 4
// 249.253 us; speedup vs baseline: 1.0114x; 1.0114x over previous
//
#include <hip/hip_runtime.h>
#include <math.h>

// Problem constants (reference: n=8192, d=4096, fp32)
#define NROWS 8192
#define NCOLS 4096
#define NCOLS4 (NCOLS / 4)
#define TEMP_INV 0.01f            // 1/TEMPERATURE

#define STRIPS 4                  // column strips of 1024 floats
#define CHUNKS 512                // row chunks
#define CHUNK_ROWS (NROWS / CHUNKS)   // 16
#define STREAM_BLKS (STRIPS * CHUNKS) // 2048 blocks, 8 per CU

// ---- Kernel A: per-chunk partial column sums (pure stores) -----------------
__global__ __launch_bounds__(256)
void colsum_partial_kernel(const float* __restrict__ g,
                           float* __restrict__ partial) {
    const int strip = blockIdx.x & (STRIPS - 1);
    const int chunk = blockIdx.x >> 2;
    const int col   = strip * 1024 + threadIdx.x * 4;
    const float* p  = g + (size_t)chunk * CHUNK_ROWS * NCOLS + col;
    float4 acc = make_float4(0.f, 0.f, 0.f, 0.f);
    #pragma unroll
    for (int r = 0; r < CHUNK_ROWS; ++r) {
        float4 v = *reinterpret_cast<const float4*>(p);
        acc.x += v.x; acc.y += v.y; acc.z += v.z; acc.w += v.w;
        p += NCOLS;
    }
    *reinterpret_cast<float4*>(partial + (size_t)chunk * NCOLS + col) = acc;
}

// ---- Kernel B/F: reduce partial[CHUNKS][NCOLS] -> dst[NCOLS] ---------------
// grid 64 blocks x 256 threads; 16 f4-cols per block, 16 chunk-groups
__global__ __launch_bounds__(256)
void reduce_kernel(const float* __restrict__ partial, float* __restrict__ dst) {
    const int tid = threadIdx.x;
    const int f4  = blockIdx.x * 16 + (tid & 15);
    const int grp = tid >> 4;                 // 16 groups
    const float4* p4 = reinterpret_cast<const float4*>(partial);
    float4 acc = make_float4(0.f, 0.f, 0.f, 0.f);
    for (int c = grp; c < CHUNKS; c += 16) {
        float4 v = p4[(size_t)c * NCOLS4 + f4];
        acc.x += v.x; acc.y += v.y; acc.z += v.z; acc.w += v.w;
    }
    __shared__ float4 red[256];
    red[tid] = acc;
    __syncthreads();
    #pragma unroll
    for (int s = 128; s >= 16; s >>= 1) {
        if (tid < s) {
            float4 o = red[tid + s];
            red[tid].x += o.x; red[tid].y += o.y;
            red[tid].z += o.z; red[tid].w += o.w;
        }
        __syncthreads();
    }
    if (tid < 16)
        reinterpret_cast<float4*>(dst)[blockIdx.x * 16 + tid] = red[tid];
}

// ---- Kernel C: scores[i] = G[i,:] . colsum (wave per 2 rows) ---------------
// grid 1024 blocks x 256 threads; 8 rows per block
__global__ __launch_bounds__(256)
void scores_kernel(const float* __restrict__ g, const float* __restrict__ colsum,
                   float* __restrict__ scores) {
    __shared__ float4 cs4[NCOLS4];
    for (int i = threadIdx.x; i < NCOLS4; i += 256)
        cs4[i] = reinterpret_cast<const float4*>(colsum)[i];
    __syncthreads();

    const int wave = threadIdx.x >> 6;
    const int lane = threadIdx.x & 63;
    #pragma unroll
    for (int rr = 0; rr < 2; ++rr) {
        const int row = blockIdx.x * 8 + wave * 2 + rr;
        const float4* gp = reinterpret_cast<const float4*>(g)
                         + (size_t)row * NCOLS4;
        float acc = 0.f;
        #pragma unroll
        for (int k = 0; k < 16; ++k) {
            const int idx = k * 64 + lane;
            float4 v = gp[idx];
            float4 c = cs4[idx];
            acc += v.x * c.x + v.y * c.y + v.z * c.z + v.w * c.w;
        }
        #pragma unroll
        for (int off = 32; off; off >>= 1) acc += __shfl_xor(acc, off, 64);
        if (lane == 0) scores[row] = acc;
    }
}

// ---- Kernel D: softmax over 8192 scores (single 1024-thread block) ---------
__global__ __launch_bounds__(1024)
void softmax_kernel(const float* __restrict__ scores, float* __restrict__ w) {
    __shared__ float red[16];
    const int tid = threadIdx.x;

    float local[8];
    float m = -INFINITY;
    #pragma unroll
    for (int k = 0; k < 8; ++k) {
        local[k] = scores[tid + k * 1024];
        m = fmaxf(m, local[k]);
    }
    #pragma unroll
    for (int off = 32; off; off >>= 1) m = fmaxf(m, __shfl_xor(m, off, 64));
    if ((tid & 63) == 0) red[tid >> 6] = m;
    __syncthreads();
    float gm = red[0];
    #pragma unroll
    for (int i = 1; i < 16; ++i) gm = fmaxf(gm, red[i]);
    __syncthreads();

    float e[8];
    float s = 0.f;
    #pragma unroll
    for (int k = 0; k < 8; ++k) {
        e[k] = __expf((local[k] - gm) * TEMP_INV);
        s += e[k];
    }
    #pragma unroll
    for (int off = 32; off; off >>= 1) s += __shfl_xor(s, off, 64);
    if ((tid & 63) == 0) red[tid >> 6] = s;
    __syncthreads();
    float total = 0.f;
    #pragma unroll
    for (int i = 0; i < 16; ++i) total += red[i];

    const float inv = 1.0f / total;
    #pragma unroll
    for (int k = 0; k < 8; ++k) w[tid + k * 1024] = e[k] * inv;
}

// ---- Kernel E: per-chunk partial weighted pooling (pure stores) ------------
__global__ __launch_bounds__(256)
void pool_partial_kernel(const float* __restrict__ g, const float* __restrict__ w,
                         float* __restrict__ partial) {
    const int strip = blockIdx.x & (STRIPS - 1);
    const int chunk = blockIdx.x >> 2;

    __shared__ float wsm[CHUNK_ROWS];
    if (threadIdx.x < CHUNK_ROWS)
        wsm[threadIdx.x] = w[chunk * CHUNK_ROWS + threadIdx.x];
    __syncthreads();

    const int col  = strip * 1024 + threadIdx.x * 4;
    const float* p = g + (size_t)chunk * CHUNK_ROWS * NCOLS + col;
    float4 acc = make_float4(0.f, 0.f, 0.f, 0.f);
    #pragma unroll
    for (int r = 0; r < CHUNK_ROWS; ++r) {
        const float wt = wsm[r];            // LDS broadcast, conflict-free
        float4 v = *reinterpret_cast<const float4*>(p);
        acc.x += wt * v.x; acc.y += wt * v.y;
        acc.z += wt * v.z; acc.w += wt * v.w;
        p += NCOLS;
    }
    *reinterpret_cast<float4*>(partial + (size_t)chunk * NCOLS + col) = acc;
}

extern "C" void kernel_launch(void* const* d_in, const int* in_sizes, int n_in,
                              void* d_out, int out_size, void* d_ws, size_t ws_size,
                              hipStream_t stream) {
    const float* grad = (const float*)d_in[0];
    float* out = (float*)d_out;

    // ws layout: partial [512][4096] f32 (8 MiB), colsum [4096],
    //            scores [8192], wgt [8192]
    float* partial = (float*)d_ws;
    float* colsum  = partial + (size_t)CHUNKS * NCOLS;
    float* scores  = colsum + NCOLS;
    float* wgt     = scores + NROWS;

    colsum_partial_kernel<<<STREAM_BLKS, 256, 0, stream>>>(grad, partial);
    reduce_kernel<<<64, 256, 0, stream>>>(partial, colsum);
    scores_kernel<<<NROWS / 8, 256, 0, stream>>>(grad, colsum, scores);
    softmax_kernel<<<1, 1024, 0, stream>>>(scores, wgt);
    pool_partial_kernel<<<STREAM_BLKS, 256, 0, stream>>>(grad, wgt, partial);
    reduce_kernel<<<64, 256, 0, stream>>>(partial, out);
}